// Round 8
// baseline (352.989 us; speedup 1.0000x reference)
//
#include <hip/hip_runtime.h>

// ---------------------------------------------------------------------------
// 2-layer GCN on MI355X.
//   h   = relu( Dinv (A+I) Dinv (z @ W1) + b1 )
//   out =       Dinv (A+I) Dinv (h @ W2) + b2
// R8: 7 dispatches. NSPLIT reverted (R7: split doubled per-edge scalar work,
// net loss). Scan collapsed to ONE 1024-thread block (coalesced round-robin,
// ~12us, replaces 3 dispatches). gemm1 and CSR-fill fused into one dispatch
// (independent work; MFMA tiles overlap scatter latency).
// ---------------------------------------------------------------------------

#define N_NODES 50000
#define N_EDGES 800000
#define D_IN    256
#define D_HID   256
#define D_OUT   128

#define GEMM1_MT ((N_NODES + 127) / 128)          // 391 m-tiles
#define GEMM1_BLOCKS (GEMM1_MT * (D_HID / 128))   // 782
#define FILL_BLOCKS ((N_EDGES + 255) / 256)       // 3125

typedef unsigned int uint32;
typedef unsigned short u16;

typedef __attribute__((ext_vector_type(8))) short bf16x8;   // MFMA A/B frag
typedef __attribute__((ext_vector_type(4))) float f32x4;    // MFMA C/D frag

__device__ __forceinline__ u16 f2bf_rne(float f) {
    union { float f; uint32 u; } c; c.f = f;
    uint32 u = c.u;
    u += 0x7FFFu + ((u >> 16) & 1u);
    return (u16)(u >> 16);
}
__device__ __forceinline__ float bf_lo(uint32 p) {
    union { uint32 u; float f; } c; c.u = p << 16; return c.f;
}
__device__ __forceinline__ float bf_hi(uint32 p) {
    union { uint32 u; float f; } c; c.u = p & 0xFFFF0000u; return c.f;
}

// ---------------- fused independent prep ----------------
// z->bf16, W1^T bf16, W2^T bf16, degree atomics

__global__ __launch_bounds__(256) void prep_kernel(const float* __restrict__ z,
                                                   const int* __restrict__ dst,
                                                   const float* __restrict__ W1,
                                                   const float* __restrict__ W2,
                                                   u16* __restrict__ zb,
                                                   u16* __restrict__ w1t,
                                                   u16* __restrict__ w2t,
                                                   int* __restrict__ cnt) {
    const int g = blockIdx.x * 256 + threadIdx.x;
    const int GT = gridDim.x * 256;

    for (int c = g; c < N_NODES * D_IN / 8; c += GT) {
        int i = c * 8;
        float4 a = *(const float4*)(z + i);
        float4 d = *(const float4*)(z + i + 4);
        uint4 pk;
        pk.x = (uint32)f2bf_rne(a.x) | ((uint32)f2bf_rne(a.y) << 16);
        pk.y = (uint32)f2bf_rne(a.z) | ((uint32)f2bf_rne(a.w) << 16);
        pk.z = (uint32)f2bf_rne(d.x) | ((uint32)f2bf_rne(d.y) << 16);
        pk.w = (uint32)f2bf_rne(d.z) | ((uint32)f2bf_rne(d.w) << 16);
        *(uint4*)(zb + i) = pk;
    }
    for (int idx = g; idx < D_IN * D_HID + D_HID * D_OUT; idx += GT) {
        if (idx < D_IN * D_HID) {
            int nrow = idx >> 8, kcol = idx & 255;
            w1t[idx] = f2bf_rne(W1[kcol * D_HID + nrow]);
        } else {
            int j = idx - D_IN * D_HID;
            int nrow = j >> 8, kcol = j & 255;
            w2t[j] = f2bf_rne(W2[kcol * D_OUT + nrow]);
        }
    }
    for (int i = g; i < N_EDGES; i += GT) atomicAdd(&cnt[dst[i]], 1);
}

// ---------------- single-block coalesced scan ----------------
// One 1024-thread block; 49 rounds of 1024 coalesced elements.
// Emits dinv, row_ptr (exclusive), cursor, row_ptr[n]=total.

__global__ __launch_bounds__(1024) void scan_kernel(const int* __restrict__ cnt,
                                                    float* __restrict__ dinv,
                                                    int* __restrict__ row_ptr,
                                                    int* __restrict__ cursor, int n) {
    __shared__ int wtot[16];
    __shared__ int carry;
    const int t = threadIdx.x;
    const int lane = t & 63, w = t >> 6;
    if (t == 0) carry = 0;
    __syncthreads();

    for (int base = 0; base < n; base += 1024) {
        int i = base + t;
        int v = 0;
        if (i < n) {
            v = cnt[i];
            dinv[i] = rsqrtf((float)(v + 1));
        }
        int x = v;
        #pragma unroll
        for (int off = 1; off < 64; off <<= 1) {
            int u = __shfl_up(x, off, 64);
            if (lane >= off) x += u;
        }
        if (lane == 63) wtot[w] = x;
        __syncthreads();

        int wbase = 0;
        #pragma unroll
        for (int j = 0; j < 16; ++j) if (j < w) wbase += wtot[j];
        int excl = carry + wbase + x - v;
        if (i < n) { row_ptr[i] = excl; cursor[i] = excl; }
        __syncthreads();                 // all carry/wtot reads done

        if (t == 0) {
            int s = 0;
            #pragma unroll
            for (int j = 0; j < 16; ++j) s += wtot[j];
            carry += s;
        }
        __syncthreads();                 // carry visible, wtot reusable
    }
    if (t == 0) row_ptr[n] = carry;
}

// ---------------- fused gemm1 + CSR fill ----------------
// blocks [0, GEMM1_BLOCKS): x1b = zb @ w1t^T (bf16 MFMA, 128x128 tile)
// blocks [GEMM1_BLOCKS, +FILL_BLOCKS): scatter col[cursor[dst]++] = src

__global__ __launch_bounds__(256, 4) void gemm1_fill_kernel(
        const u16* __restrict__ A, const u16* __restrict__ BT,
        u16* __restrict__ C,
        const int* __restrict__ src, const int* __restrict__ dst,
        int* __restrict__ cursor, int* __restrict__ col) {
    __shared__ short As[128 * 32];
    __shared__ short Bs[128 * 32];
    const int b = blockIdx.x;
    const int t = threadIdx.x;

    if (b >= GEMM1_BLOCKS) {             // ---- fill path ----
        int i = (b - GEMM1_BLOCKS) * 256 + t;
        if (i < N_EDGES) {
            int d = dst[i];
            int s = src[i];
            int pos = atomicAdd(&cursor[d], 1);
            col[pos] = s;
        }
        return;
    }

    // ---- gemm path ----
    const int K = 256, M = N_NODES, NT = D_HID;
    const int m0 = (b % GEMM1_MT) * 128;
    const int n0 = (b / GEMM1_MT) * 128;
    const int w  = t >> 6;
    const int lane = t & 63;
    const int lm = lane & 15;
    const int lq = lane >> 4;
    const int wm = w & 1;
    const int wn = w >> 1;

    f32x4 acc[4][4] = {};

    for (int k0 = 0; k0 < K; k0 += 32) {
        #pragma unroll
        for (int j = 0; j < 2; ++j) {
            int c = w * 128 + j * 64 + lane;
            int row = c >> 2;
            int kc = k0 + (c & 3) * 8;
            int gm = m0 + row; if (gm >= M) gm = M - 1;
            const u16* gpa = A  + (size_t)gm * K + kc;
            const u16* gpb = BT + (size_t)(n0 + row) * K + kc;
            __builtin_amdgcn_global_load_lds(
                (const __attribute__((address_space(1))) void*)gpa,
                (__attribute__((address_space(3))) void*)(As + (w * 128 + j * 64) * 8),
                16, 0, 0);
            __builtin_amdgcn_global_load_lds(
                (const __attribute__((address_space(1))) void*)gpb,
                (__attribute__((address_space(3))) void*)(Bs + (w * 128 + j * 64) * 8),
                16, 0, 0);
        }
        __syncthreads();

        bf16x8 af[4], bf[4];
        #pragma unroll
        for (int mt = 0; mt < 4; ++mt)
            af[mt] = *(const bf16x8*)&As[(wm * 64 + mt * 16 + lm) * 32 + lq * 8];
        #pragma unroll
        for (int nt = 0; nt < 4; ++nt)
            bf[nt] = *(const bf16x8*)&Bs[(wn * 64 + nt * 16 + lm) * 32 + lq * 8];

        #pragma unroll
        for (int mt = 0; mt < 4; ++mt)
            #pragma unroll
            for (int nt = 0; nt < 4; ++nt)
                acc[mt][nt] = __builtin_amdgcn_mfma_f32_16x16x32_bf16(
                    af[mt], bf[nt], acc[mt][nt], 0, 0, 0);

        __syncthreads();
    }

    #pragma unroll
    for (int mt = 0; mt < 4; ++mt) {
        #pragma unroll
        for (int r = 0; r < 4; ++r) {
            int gm = m0 + wm * 64 + mt * 16 + lq * 4 + r;
            if (gm < M) {
                #pragma unroll
                for (int nt = 0; nt < 4; ++nt) {
                    int gn = n0 + wn * 64 + nt * 16 + lm;
                    C[(size_t)gm * NT + gn] = f2bf_rne(acc[mt][nt][r]);
                }
            }
        }
    }
}

// ---------------- bf16 MFMA GEMM (standalone, for layer 2) ----------------

template <int NT>
__global__ __launch_bounds__(256, 4) void gemm_bf16_kernel(const u16* __restrict__ A,
                                                           const u16* __restrict__ BT,
                                                           u16* __restrict__ C, int M) {
    const int K = 256;
    __shared__ short As[128 * 32];
    __shared__ short Bs[128 * 32];

    const int m0 = blockIdx.x * 128;
    const int n0 = blockIdx.y * 128;
    const int t  = threadIdx.x;
    const int w  = t >> 6;
    const int lane = t & 63;
    const int lm = lane & 15;
    const int lq = lane >> 4;
    const int wm = w & 1;
    const int wn = w >> 1;

    f32x4 acc[4][4] = {};

    for (int k0 = 0; k0 < K; k0 += 32) {
        #pragma unroll
        for (int j = 0; j < 2; ++j) {
            int c = w * 128 + j * 64 + lane;
            int row = c >> 2;
            int kc = k0 + (c & 3) * 8;
            int gm = m0 + row; if (gm >= M) gm = M - 1;
            const u16* gpa = A  + (size_t)gm * K + kc;
            const u16* gpb = BT + (size_t)(n0 + row) * K + kc;
            __builtin_amdgcn_global_load_lds(
                (const __attribute__((address_space(1))) void*)gpa,
                (__attribute__((address_space(3))) void*)(As + (w * 128 + j * 64) * 8),
                16, 0, 0);
            __builtin_amdgcn_global_load_lds(
                (const __attribute__((address_space(1))) void*)gpb,
                (__attribute__((address_space(3))) void*)(Bs + (w * 128 + j * 64) * 8),
                16, 0, 0);
        }
        __syncthreads();

        bf16x8 af[4], bf[4];
        #pragma unroll
        for (int mt = 0; mt < 4; ++mt)
            af[mt] = *(const bf16x8*)&As[(wm * 64 + mt * 16 + lm) * 32 + lq * 8];
        #pragma unroll
        for (int nt = 0; nt < 4; ++nt)
            bf[nt] = *(const bf16x8*)&Bs[(wn * 64 + nt * 16 + lm) * 32 + lq * 8];

        #pragma unroll
        for (int mt = 0; mt < 4; ++mt)
            #pragma unroll
            for (int nt = 0; nt < 4; ++nt)
                acc[mt][nt] = __builtin_amdgcn_mfma_f32_16x16x32_bf16(
                    af[mt], bf[nt], acc[mt][nt], 0, 0, 0);

        __syncthreads();
    }

    #pragma unroll
    for (int mt = 0; mt < 4; ++mt) {
        #pragma unroll
        for (int r = 0; r < 4; ++r) {
            int gm = m0 + wm * 64 + mt * 16 + lq * 4 + r;
            if (gm < M) {
                #pragma unroll
                for (int nt = 0; nt < 4; ++nt) {
                    int gn = n0 + wn * 64 + nt * 16 + lm;
                    C[(size_t)gm * NT + gn] = f2bf_rne(acc[mt][nt][r]);
                }
            }
        }
    }
}

// ---------------- Aggregation: one wave per node, bf16 gather over CSR ----------------

template <int D, bool RELU, bool OUTBF>
__global__ __launch_bounds__(256) void aggregate_kernel(const u16* __restrict__ x,
                                                        const int* __restrict__ row_ptr,
                                                        const int* __restrict__ col,
                                                        const float* __restrict__ dinv,
                                                        const float* __restrict__ bias,
                                                        void* __restrict__ outp, int n_nodes) {
    constexpr int VPL = D / 64;
    int node = (blockIdx.x * blockDim.x + threadIdx.x) >> 6;
    int lane = threadIdx.x & 63;
    if (node >= n_nodes) return;
    const int c0 = lane * VPL;

    float di = dinv[node];
    float acc[4][VPL] = {};

    {
        float w = di * di;
        const u16* xs = x + (size_t)node * D + c0;
        if constexpr (VPL == 4) {
            uint2 p = *(const uint2*)xs;
            acc[0][0] = bf_lo(p.x) * w;
            acc[0][1] = bf_hi(p.x) * w;
            acc[0][2] = bf_lo(p.y) * w;
            acc[0][3] = bf_hi(p.y) * w;
        } else {
            uint32 p = *(const uint32*)xs;
            acc[0][0] = bf_lo(p) * w;
            acc[0][1] = bf_hi(p) * w;
        }
    }

    int e0 = row_ptr[node], e1 = row_ptr[node + 1];
    int e = e0;
    for (; e + 4 <= e1; e += 4) {
        #pragma unroll
        for (int u = 0; u < 4; ++u) {
            int s  = col[e + u];
            float w = dinv[s] * di;
            const u16* xs = x + (size_t)s * D + c0;
            if constexpr (VPL == 4) {
                uint2 p = *(const uint2*)xs;
                acc[u][0] = fmaf(bf_lo(p.x), w, acc[u][0]);
                acc[u][1] = fmaf(bf_hi(p.x), w, acc[u][1]);
                acc[u][2] = fmaf(bf_lo(p.y), w, acc[u][2]);
                acc[u][3] = fmaf(bf_hi(p.y), w, acc[u][3]);
            } else {
                uint32 p = *(const uint32*)xs;
                acc[u][0] = fmaf(bf_lo(p), w, acc[u][0]);
                acc[u][1] = fmaf(bf_hi(p), w, acc[u][1]);
            }
        }
    }
    for (; e < e1; ++e) {
        int s  = col[e];
        float w = dinv[s] * di;
        const u16* xs = x + (size_t)s * D + c0;
        if constexpr (VPL == 4) {
            uint2 p = *(const uint2*)xs;
            acc[0][0] = fmaf(bf_lo(p.x), w, acc[0][0]);
            acc[0][1] = fmaf(bf_hi(p.x), w, acc[0][1]);
            acc[0][2] = fmaf(bf_lo(p.y), w, acc[0][2]);
            acc[0][3] = fmaf(bf_hi(p.y), w, acc[0][3]);
        } else {
            uint32 p = *(const uint32*)xs;
            acc[0][0] = fmaf(bf_lo(p), w, acc[0][0]);
            acc[0][1] = fmaf(bf_hi(p), w, acc[0][1]);
        }
    }

    float v[VPL];
    #pragma unroll
    for (int j = 0; j < VPL; ++j) {
        float s = acc[0][j] + acc[1][j] + acc[2][j] + acc[3][j] + bias[c0 + j];
        v[j] = RELU ? fmaxf(s, 0.0f) : s;
    }

    if constexpr (OUTBF) {
        u16* op = (u16*)outp + (size_t)node * D + c0;
        if constexpr (VPL == 4) {
            uint2 pk;
            pk.x = (uint32)f2bf_rne(v[0]) | ((uint32)f2bf_rne(v[1]) << 16);
            pk.y = (uint32)f2bf_rne(v[2]) | ((uint32)f2bf_rne(v[3]) << 16);
            *(uint2*)op = pk;
        } else {
            *(uint32*)op = (uint32)f2bf_rne(v[0]) | ((uint32)f2bf_rne(v[1]) << 16);
        }
    } else {
        float* op = (float*)outp + (size_t)node * D + c0;
        #pragma unroll
        for (int j = 0; j < VPL; ++j) op[j] = v[j];
    }
}

// ---------------- launcher ----------------

extern "C" void kernel_launch(void* const* d_in, const int* in_sizes, int n_in,
                              void* d_out, int out_size, void* d_ws, size_t ws_size,
                              hipStream_t stream) {
    const float* z  = (const float*)d_in[0];
    const int*   ei = (const int*)d_in[1];
    const float* W1 = (const float*)d_in[2];
    const float* b1 = (const float*)d_in[3];
    const float* W2 = (const float*)d_in[4];
    const float* b2 = (const float*)d_in[5];
    float* out = (float*)d_out;

    const int Nn = N_NODES, E = N_EDGES;
    const int* srcp = ei;
    const int* dstp = ei + E;

    char* ws = (char*)d_ws;
    size_t off = 0;
    auto alloc = [&](size_t bytes) -> char* {
        char* p = ws + off;
        off += (bytes + 511) & ~(size_t)511;
        return p;
    };
    u16*   zb     = (u16*)  alloc((size_t)Nn * D_IN * 2);
    u16*   w1t    = (u16*)  alloc((size_t)D_IN * D_HID * 2);
    u16*   w2t    = (u16*)  alloc((size_t)D_HID * D_OUT * 2);
    u16*   x1b    = (u16*)  alloc((size_t)Nn * D_HID * 2);
    u16*   hb     = (u16*)  alloc((size_t)Nn * D_HID * 2);
    u16*   h2b    = (u16*)  alloc((size_t)Nn * D_OUT * 2);
    int*   cnt    = (int*)  alloc((size_t)Nn * 4);
    float* dinv   = (float*)alloc((size_t)Nn * 4);
    int*   row_ptr= (int*)  alloc((size_t)(Nn + 1) * 4);
    int*   cursor = (int*)  alloc((size_t)Nn * 4);
    int*   col    = (int*)  alloc((size_t)E * 4);

    hipMemsetAsync(cnt, 0, (size_t)Nn * 4, stream);
    prep_kernel<<<1024, 256, 0, stream>>>(z, dstp, W1, W2, zb, w1t, w2t, cnt);
    scan_kernel<<<1, 1024, 0, stream>>>(cnt, dinv, row_ptr, cursor, Nn);
    gemm1_fill_kernel<<<GEMM1_BLOCKS + FILL_BLOCKS, 256, 0, stream>>>(
        zb, w1t, x1b, srcp, dstp, cursor, col);
    {
        int blocks = (Nn + 3) / 4;     // one wave per node
        aggregate_kernel<D_HID, true, true><<<blocks, 256, 0, stream>>>(x1b, row_ptr, col, dinv, b1, hb, Nn);
    }
    {
        dim3 grid((Nn + 127) / 128, D_OUT / 128);
        gemm_bf16_kernel<D_OUT><<<grid, 256, 0, stream>>>(hb, w2t, h2b, Nn);
    }
    {
        int blocks = (Nn + 3) / 4;
        aggregate_kernel<D_OUT, false, false><<<blocks, 256, 0, stream>>>(h2b, row_ptr, col, dinv, b2, out, Nn);
    }
}

// Round 9
// 298.044 us; speedup vs baseline: 1.1844x; 1.1844x over previous
//
#include <hip/hip_runtime.h>

// ---------------------------------------------------------------------------
// 2-layer GCN on MI355X.
//   h   = relu( Dinv (A+I) Dinv (z @ W1) + b1 )
//   out =       Dinv (A+I) Dinv (h @ W2) + b2
// R9: degree pass now saves its atomicAdd return as rank[i]; fill becomes
// atomic-free deterministic placement col[row_ptr[d]+rank] = src. Scan
// vectorized int4 (13 rounds). R8's gemm1+fill fusion reverted (no overlap
// materialized: blockIdx order serializes the two phases).
// 8 dispatches: memset, prep, scan, fill, gemm1, agg1, gemm2, agg2.
// ---------------------------------------------------------------------------

#define N_NODES 50000
#define N_EDGES 800000
#define D_IN    256
#define D_HID   256
#define D_OUT   128

typedef unsigned int uint32;
typedef unsigned short u16;

typedef __attribute__((ext_vector_type(8))) short bf16x8;   // MFMA A/B frag
typedef __attribute__((ext_vector_type(4))) float f32x4;    // MFMA C/D frag

__device__ __forceinline__ u16 f2bf_rne(float f) {
    union { float f; uint32 u; } c; c.f = f;
    uint32 u = c.u;
    u += 0x7FFFu + ((u >> 16) & 1u);
    return (u16)(u >> 16);
}
__device__ __forceinline__ float bf_lo(uint32 p) {
    union { uint32 u; float f; } c; c.u = p << 16; return c.f;
}
__device__ __forceinline__ float bf_hi(uint32 p) {
    union { uint32 u; float f; } c; c.u = p & 0xFFFF0000u; return c.f;
}

// ---------------- fused independent prep ----------------
// z->bf16, W1^T bf16, W2^T bf16, degree atomics WITH rank capture.

__global__ __launch_bounds__(256) void prep_kernel(const float* __restrict__ z,
                                                   const int* __restrict__ dst,
                                                   const float* __restrict__ W1,
                                                   const float* __restrict__ W2,
                                                   u16* __restrict__ zb,
                                                   u16* __restrict__ w1t,
                                                   u16* __restrict__ w2t,
                                                   int* __restrict__ cnt,
                                                   int* __restrict__ rank) {
    const int g = blockIdx.x * 256 + threadIdx.x;
    const int GT = gridDim.x * 256;

    for (int c = g; c < N_NODES * D_IN / 8; c += GT) {
        int i = c * 8;
        float4 a = *(const float4*)(z + i);
        float4 d = *(const float4*)(z + i + 4);
        uint4 pk;
        pk.x = (uint32)f2bf_rne(a.x) | ((uint32)f2bf_rne(a.y) << 16);
        pk.y = (uint32)f2bf_rne(a.z) | ((uint32)f2bf_rne(a.w) << 16);
        pk.z = (uint32)f2bf_rne(d.x) | ((uint32)f2bf_rne(d.y) << 16);
        pk.w = (uint32)f2bf_rne(d.z) | ((uint32)f2bf_rne(d.w) << 16);
        *(uint4*)(zb + i) = pk;
    }
    for (int idx = g; idx < D_IN * D_HID + D_HID * D_OUT; idx += GT) {
        if (idx < D_IN * D_HID) {
            int nrow = idx >> 8, kcol = idx & 255;
            w1t[idx] = f2bf_rne(W1[kcol * D_HID + nrow]);
        } else {
            int j = idx - D_IN * D_HID;
            int nrow = j >> 8, kcol = j & 255;
            w2t[j] = f2bf_rne(W2[kcol * D_OUT + nrow]);
        }
    }
    for (int i = g; i < N_EDGES; i += GT)
        rank[i] = atomicAdd(&cnt[dst[i]], 1);
}

// ---------------- single-block vectorized scan ----------------
// 1024 threads x int4 -> 13 rounds over 50000 elements (n % 4 == 0).

__global__ __launch_bounds__(1024) void scan_kernel(const int* __restrict__ cnt,
                                                    float* __restrict__ dinv,
                                                    int* __restrict__ row_ptr, int n) {
    __shared__ int wtot[16];
    __shared__ int carry_s;
    const int t = threadIdx.x;
    const int lane = t & 63, w = t >> 6;
    if (t == 0) carry_s = 0;
    __syncthreads();

    const int n4 = n >> 2;
    for (int base = 0; base < n4; base += 1024) {
        int i4 = base + t;
        int4 v = make_int4(0, 0, 0, 0);
        if (i4 < n4) v = ((const int4*)cnt)[i4];
        int s = v.x + v.y + v.z + v.w;
        int x = s;
        #pragma unroll
        for (int off = 1; off < 64; off <<= 1) {
            int u = __shfl_up(x, off, 64);
            if (lane >= off) x += u;
        }
        if (lane == 63) wtot[w] = x;
        __syncthreads();

        int wbase = 0;
        #pragma unroll
        for (int j = 0; j < 16; ++j) if (j < w) wbase += wtot[j];
        int excl = carry_s + wbase + x - s;
        if (i4 < n4) {
            int4 rp;
            rp.x = excl;
            rp.y = rp.x + v.x;
            rp.z = rp.y + v.y;
            rp.w = rp.z + v.z;
            ((int4*)row_ptr)[i4] = rp;
            float4 dv;
            dv.x = rsqrtf((float)(v.x + 1));
            dv.y = rsqrtf((float)(v.y + 1));
            dv.z = rsqrtf((float)(v.z + 1));
            dv.w = rsqrtf((float)(v.w + 1));
            ((float4*)dinv)[i4] = dv;
        }
        __syncthreads();
        if (t == 0) {
            int tot = 0;
            #pragma unroll
            for (int j = 0; j < 16; ++j) tot += wtot[j];
            carry_s += tot;
        }
        __syncthreads();
    }
    if (t == 0) row_ptr[n] = carry_s;
}

// ---------------- atomic-free CSR fill ----------------

__global__ void fill_kernel(const int* __restrict__ src, const int* __restrict__ dst,
                            const int* __restrict__ rank, const int* __restrict__ row_ptr,
                            int* __restrict__ col, int n_edges) {
    int i = blockIdx.x * blockDim.x + threadIdx.x;
    if (i < n_edges)
        col[row_ptr[dst[i]] + rank[i]] = src[i];
}

// ---------------- bf16 MFMA GEMM ----------------

template <int NT>
__global__ __launch_bounds__(256, 4) void gemm_bf16_kernel(const u16* __restrict__ A,
                                                           const u16* __restrict__ BT,
                                                           u16* __restrict__ C, int M) {
    const int K = 256;
    __shared__ short As[128 * 32];
    __shared__ short Bs[128 * 32];

    const int m0 = blockIdx.x * 128;
    const int n0 = blockIdx.y * 128;
    const int t  = threadIdx.x;
    const int w  = t >> 6;
    const int lane = t & 63;
    const int lm = lane & 15;
    const int lq = lane >> 4;
    const int wm = w & 1;
    const int wn = w >> 1;

    f32x4 acc[4][4] = {};

    for (int k0 = 0; k0 < K; k0 += 32) {
        #pragma unroll
        for (int j = 0; j < 2; ++j) {
            int c = w * 128 + j * 64 + lane;
            int row = c >> 2;
            int kc = k0 + (c & 3) * 8;
            int gm = m0 + row; if (gm >= M) gm = M - 1;
            const u16* gpa = A  + (size_t)gm * K + kc;
            const u16* gpb = BT + (size_t)(n0 + row) * K + kc;
            __builtin_amdgcn_global_load_lds(
                (const __attribute__((address_space(1))) void*)gpa,
                (__attribute__((address_space(3))) void*)(As + (w * 128 + j * 64) * 8),
                16, 0, 0);
            __builtin_amdgcn_global_load_lds(
                (const __attribute__((address_space(1))) void*)gpb,
                (__attribute__((address_space(3))) void*)(Bs + (w * 128 + j * 64) * 8),
                16, 0, 0);
        }
        __syncthreads();

        bf16x8 af[4], bf[4];
        #pragma unroll
        for (int mt = 0; mt < 4; ++mt)
            af[mt] = *(const bf16x8*)&As[(wm * 64 + mt * 16 + lm) * 32 + lq * 8];
        #pragma unroll
        for (int nt = 0; nt < 4; ++nt)
            bf[nt] = *(const bf16x8*)&Bs[(wn * 64 + nt * 16 + lm) * 32 + lq * 8];

        #pragma unroll
        for (int mt = 0; mt < 4; ++mt)
            #pragma unroll
            for (int nt = 0; nt < 4; ++nt)
                acc[mt][nt] = __builtin_amdgcn_mfma_f32_16x16x32_bf16(
                    af[mt], bf[nt], acc[mt][nt], 0, 0, 0);

        __syncthreads();
    }

    #pragma unroll
    for (int mt = 0; mt < 4; ++mt) {
        #pragma unroll
        for (int r = 0; r < 4; ++r) {
            int gm = m0 + wm * 64 + mt * 16 + lq * 4 + r;
            if (gm < M) {
                #pragma unroll
                for (int nt = 0; nt < 4; ++nt) {
                    int gn = n0 + wn * 64 + nt * 16 + lm;
                    C[(size_t)gm * NT + gn] = f2bf_rne(acc[mt][nt][r]);
                }
            }
        }
    }
}

// ---------------- Aggregation: one wave per node, bf16 gather over CSR ----------------

template <int D, bool RELU, bool OUTBF>
__global__ __launch_bounds__(256) void aggregate_kernel(const u16* __restrict__ x,
                                                        const int* __restrict__ row_ptr,
                                                        const int* __restrict__ col,
                                                        const float* __restrict__ dinv,
                                                        const float* __restrict__ bias,
                                                        void* __restrict__ outp, int n_nodes) {
    constexpr int VPL = D / 64;
    int node = (blockIdx.x * blockDim.x + threadIdx.x) >> 6;
    int lane = threadIdx.x & 63;
    if (node >= n_nodes) return;
    const int c0 = lane * VPL;

    float di = dinv[node];
    float acc[4][VPL] = {};

    {
        float w = di * di;
        const u16* xs = x + (size_t)node * D + c0;
        if constexpr (VPL == 4) {
            uint2 p = *(const uint2*)xs;
            acc[0][0] = bf_lo(p.x) * w;
            acc[0][1] = bf_hi(p.x) * w;
            acc[0][2] = bf_lo(p.y) * w;
            acc[0][3] = bf_hi(p.y) * w;
        } else {
            uint32 p = *(const uint32*)xs;
            acc[0][0] = bf_lo(p) * w;
            acc[0][1] = bf_hi(p) * w;
        }
    }

    int e0 = row_ptr[node], e1 = row_ptr[node + 1];
    int e = e0;
    for (; e + 4 <= e1; e += 4) {
        #pragma unroll
        for (int u = 0; u < 4; ++u) {
            int s  = col[e + u];
            float w = dinv[s] * di;
            const u16* xs = x + (size_t)s * D + c0;
            if constexpr (VPL == 4) {
                uint2 p = *(const uint2*)xs;
                acc[u][0] = fmaf(bf_lo(p.x), w, acc[u][0]);
                acc[u][1] = fmaf(bf_hi(p.x), w, acc[u][1]);
                acc[u][2] = fmaf(bf_lo(p.y), w, acc[u][2]);
                acc[u][3] = fmaf(bf_hi(p.y), w, acc[u][3]);
            } else {
                uint32 p = *(const uint32*)xs;
                acc[u][0] = fmaf(bf_lo(p), w, acc[u][0]);
                acc[u][1] = fmaf(bf_hi(p), w, acc[u][1]);
            }
        }
    }
    for (; e < e1; ++e) {
        int s  = col[e];
        float w = dinv[s] * di;
        const u16* xs = x + (size_t)s * D + c0;
        if constexpr (VPL == 4) {
            uint2 p = *(const uint2*)xs;
            acc[0][0] = fmaf(bf_lo(p.x), w, acc[0][0]);
            acc[0][1] = fmaf(bf_hi(p.x), w, acc[0][1]);
            acc[0][2] = fmaf(bf_lo(p.y), w, acc[0][2]);
            acc[0][3] = fmaf(bf_hi(p.y), w, acc[0][3]);
        } else {
            uint32 p = *(const uint32*)xs;
            acc[0][0] = fmaf(bf_lo(p), w, acc[0][0]);
            acc[0][1] = fmaf(bf_hi(p), w, acc[0][1]);
        }
    }

    float v[VPL];
    #pragma unroll
    for (int j = 0; j < VPL; ++j) {
        float s = acc[0][j] + acc[1][j] + acc[2][j] + acc[3][j] + bias[c0 + j];
        v[j] = RELU ? fmaxf(s, 0.0f) : s;
    }

    if constexpr (OUTBF) {
        u16* op = (u16*)outp + (size_t)node * D + c0;
        if constexpr (VPL == 4) {
            uint2 pk;
            pk.x = (uint32)f2bf_rne(v[0]) | ((uint32)f2bf_rne(v[1]) << 16);
            pk.y = (uint32)f2bf_rne(v[2]) | ((uint32)f2bf_rne(v[3]) << 16);
            *(uint2*)op = pk;
        } else {
            *(uint32*)op = (uint32)f2bf_rne(v[0]) | ((uint32)f2bf_rne(v[1]) << 16);
        }
    } else {
        float* op = (float*)outp + (size_t)node * D + c0;
        #pragma unroll
        for (int j = 0; j < VPL; ++j) op[j] = v[j];
    }
}

// ---------------- launcher ----------------

extern "C" void kernel_launch(void* const* d_in, const int* in_sizes, int n_in,
                              void* d_out, int out_size, void* d_ws, size_t ws_size,
                              hipStream_t stream) {
    const float* z  = (const float*)d_in[0];
    const int*   ei = (const int*)d_in[1];
    const float* W1 = (const float*)d_in[2];
    const float* b1 = (const float*)d_in[3];
    const float* W2 = (const float*)d_in[4];
    const float* b2 = (const float*)d_in[5];
    float* out = (float*)d_out;

    const int Nn = N_NODES, E = N_EDGES;
    const int* srcp = ei;
    const int* dstp = ei + E;

    char* ws = (char*)d_ws;
    size_t off = 0;
    auto alloc = [&](size_t bytes) -> char* {
        char* p = ws + off;
        off += (bytes + 511) & ~(size_t)511;
        return p;
    };
    u16*   zb     = (u16*)  alloc((size_t)Nn * D_IN * 2);
    u16*   w1t    = (u16*)  alloc((size_t)D_IN * D_HID * 2);
    u16*   w2t    = (u16*)  alloc((size_t)D_HID * D_OUT * 2);
    u16*   x1b    = (u16*)  alloc((size_t)Nn * D_HID * 2);
    u16*   hb     = (u16*)  alloc((size_t)Nn * D_HID * 2);
    u16*   h2b    = (u16*)  alloc((size_t)Nn * D_OUT * 2);
    int*   cnt    = (int*)  alloc((size_t)Nn * 4);
    float* dinv   = (float*)alloc((size_t)Nn * 4);
    int*   row_ptr= (int*)  alloc((size_t)(Nn + 1) * 4);
    int*   rank   = (int*)  alloc((size_t)E * 4);
    int*   col    = (int*)  alloc((size_t)E * 4);

    hipMemsetAsync(cnt, 0, (size_t)Nn * 4, stream);
    prep_kernel<<<1024, 256, 0, stream>>>(z, dstp, W1, W2, zb, w1t, w2t, cnt, rank);
    scan_kernel<<<1, 1024, 0, stream>>>(cnt, dinv, row_ptr, Nn);
    fill_kernel<<<(E + 255) / 256, 256, 0, stream>>>(srcp, dstp, rank, row_ptr, col, E);
    {
        dim3 grid((Nn + 127) / 128, D_HID / 128);
        gemm_bf16_kernel<D_HID><<<grid, 256, 0, stream>>>(zb, w1t, x1b, Nn);
    }
    {
        int blocks = (Nn + 3) / 4;     // one wave per node
        aggregate_kernel<D_HID, true, true><<<blocks, 256, 0, stream>>>(x1b, row_ptr, col, dinv, b1, hb, Nn);
    }
    {
        dim3 grid((Nn + 127) / 128, D_OUT / 128);
        gemm_bf16_kernel<D_OUT><<<grid, 256, 0, stream>>>(hb, w2t, h2b, Nn);
    }
    {
        int blocks = (Nn + 3) / 4;
        aggregate_kernel<D_OUT, false, false><<<blocks, 256, 0, stream>>>(h2b, row_ptr, col, dinv, b2, out, Nn);
    }
}